// Round 8
// baseline (2011.672 us; speedup 1.0000x reference)
//
#include <hip/hip_runtime.h>
#include <hip/hip_bf16.h>
#include <cstdint>
#include <cstddef>

// Problem dims (fixed by setup_inputs)
#define TDIM 2048
#define HDIM 4096
#define MDIM 14336

typedef __attribute__((ext_vector_type(8))) __bf16 bf16x8;
typedef __attribute__((ext_vector_type(4))) float f32x4;

__device__ __constant__ float NF4_LUT[16] = {
    -1.0f, -0.6961928009986877f, -0.5250730514526367f, -0.39491748809814453f,
    -0.28444138169288635f, -0.18477343022823334f, -0.09105003625154495f, 0.0f,
    0.07958029955625534f, 0.16093020141124725f, 0.24611230194568634f,
    0.33791524171829224f, 0.44070982933044434f, 0.5626170039176941f,
    0.7229568362236023f, 1.0f};

__device__ __forceinline__ void g2l16(const void* g, void* l) {
  __builtin_amdgcn_global_load_lds(
      (const __attribute__((address_space(1))) unsigned int*)g,
      (__attribute__((address_space(3))) unsigned int*)l, 16, 0, 0);
}

// ------------------------------------------------------------ x f32 -> bf16
__global__ __launch_bounds__(256) void f32_to_bf16_k(
    const float* __restrict__ in, __hip_bfloat16* __restrict__ out, int n8) {
  for (int i = blockIdx.x * 256 + threadIdx.x; i < n8; i += gridDim.x * 256) {
    const float4* p = (const float4*)(in + (size_t)i * 8);
    float4 a = p[0], b = p[1];
    union { __hip_bfloat16 h[8]; int4 v; } u;
    u.h[0] = __float2bfloat16(a.x);
    u.h[1] = __float2bfloat16(a.y);
    u.h[2] = __float2bfloat16(a.z);
    u.h[3] = __float2bfloat16(a.w);
    u.h[4] = __float2bfloat16(b.x);
    u.h[5] = __float2bfloat16(b.y);
    u.h[6] = __float2bfloat16(b.z);
    u.h[7] = __float2bfloat16(b.w);
    *(int4*)(out + (size_t)i * 8) = u.v;
  }
}

// ----------------------------------------- Fused NF4-dequant 128x128 GEMM
// C[M,N] = A[M,K] @ dequant(Bc,Bam)[N,K]^T, f32 acc.
// R1-proven loop skeleton (single-buffer, 2x __syncthreads, 4 waves 2x2,
// BK=64, global_load_lds A staging, XOR-swizzled LDS) with B staged by
// IN-KERNEL dequant: per K-tile each thread loads 32 int32 codes (128 B),
// looks up code-PAIRS in a 256-entry float2 LDS LUT, scales by the
// per-(row, 64-block) absmax (BK=64 == quant blocksize, 1 scalar/tile),
// converts RNE to bf16, and ds_write_b128's into the same swizzled layout
// the R1 read path expects (write-side swizzle legal: not global_load_lds).
// Codes for kt+1 are register-prefetched under the MFMA phase (T14).
// bn-MAJOR wg order (+XCD swizzle): the 16 bm-blocks sharing a 2 MB code
// panel run concurrently -> codes read ~once from HBM, L2-served after.
// EPI: 0 = store bf16; 1 = silu(Gin)*acc -> bf16; 2 = store f32
template <int EPI>
__global__ __launch_bounds__(256, 3) void gemm_fused_k(
    const __hip_bfloat16* __restrict__ A, const int* __restrict__ Bc,
    const float* __restrict__ Bam, void* __restrict__ Cv,
    const __hip_bfloat16* __restrict__ Gin, int M, int N, int K) {
  __shared__ __align__(16) char sA[128 * 128];
  __shared__ __align__(16) char sB[128 * 128];
  __shared__ float2 lut2[256];

  const int tid = threadIdx.x;
  const int lane = tid & 63;
  const int wid = tid >> 6;

  // pair LUT: entry i = (NF4[i&15], NF4[i>>4])  (c0 low nibble, c1 high)
  lut2[tid] = make_float2(NF4_LUT[tid & 15], NF4_LUT[tid >> 4]);

  // bijective XCD swizzle (grids 1792/512, both %8==0), bn-major decode
  const int nbm = M >> 7;
  const int nbn = N >> 7;
  const int nwg = nbm * nbn;
  const int q8 = nwg >> 3;
  const int bid = blockIdx.x;
  const int wg = (bid & 7) * q8 + (bid >> 3);
  const int bn = wg / nbm;       // consecutive wgs share bn (B-panel L2 reuse)
  const int bm = wg - bn * nbm;

  // ---- A staging geometry (R1-exact)
  const int srow = lane >> 3;
  const int scolb = ((lane & 7) ^ srow) << 4;  // pre-swizzled source col
  const char* gA = (const char*)A +
      ((size_t)(bm * 128 + wid * 8 + srow) * K) * 2 + scolb;
  const size_t cstep = (size_t)64 * K;  // 32 rows, in bytes
  char* lA = sA + wid * 1024;           // wave-uniform LDS dest base

  // ---- B fused-dequant geometry: 2 threads/row, 32 codes each
  const int r = tid >> 1;   // 0..127: B tile row
  const int h = tid & 1;    // half of the 64-col K-tile
  const int Rrow = bn * 128 + r;
  const int* cbase = Bc + (size_t)Rrow * K + h * 32;
  const float* amrow = Bam + (size_t)Rrow * (K >> 6);
  char* bwr = sB + r * 128;
  const int rx = r & 7;

  // ---- fragment read bases (swizzled) — R1-exact
  const int wm = wid >> 1, wn = wid & 1;
  const int colsw = (((lane >> 4) << 4) ^ ((lane & 7) << 4));
  const int aoff = (wm * 64 + (lane & 15)) * 128 + colsw;
  const int boff = (wn * 64 + (lane & 15)) * 128 + colsw;

  f32x4 acc[4][4] = {};

  const int nt = K >> 6;
  union { int w[32]; int4 v4[8]; } cw;
#pragma unroll
  for (int q = 0; q < 8; ++q) cw.v4[q] = ((const int4*)cbase)[q];
  float am = amrow[0];

  __syncthreads();  // lut2 visible

  for (int kt = 0; kt < nt; ++kt) {
    // ---- dequant 32 codes -> 4 swizzled 16B chunks (all indices static)
#pragma unroll
    for (int j = 0; j < 4; ++j) {
      union { __hip_bfloat16 b[8]; int4 v; } ou;
#pragma unroll
      for (int p = 0; p < 4; ++p) {
        const int w0 = cw.w[j * 8 + 2 * p];
        const int w1 = cw.w[j * 8 + 2 * p + 1];
        const float2 lv = lut2[(w0 & 15) | ((w1 & 15) << 4)];
        ou.b[2 * p] = __float2bfloat16(lv.x * am);
        ou.b[2 * p + 1] = __float2bfloat16(lv.y * am);
      }
      *(int4*)(bwr + ((((h << 2) | j) ^ rx) << 4)) = ou.v;
    }
    // ---- stage A tile kt (async -> drained at barrier)
    const char* pa = gA + (size_t)kt * 128;
#pragma unroll
    for (int c = 0; c < 4; ++c) g2l16(pa + c * cstep, lA + c * 4096);
    // ---- prefetch next codes + absmax (latency hidden under MFMA)
    if (kt + 1 < nt) {
      const int4* np = (const int4*)(cbase + (kt + 1) * 64);
#pragma unroll
      for (int q = 0; q < 8; ++q) cw.v4[q] = np[q];
      am = amrow[kt + 1];
    }
    __syncthreads();
#pragma unroll
    for (int ks = 0; ks < 2; ++ks) {
      bf16x8 af[4], bv[4];
#pragma unroll
      for (int i = 0; i < 4; ++i) {
        af[i] = *(const bf16x8*)(sA + ((aoff + i * 2048) ^ (ks << 6)));
        bv[i] = *(const bf16x8*)(sB + ((boff + i * 2048) ^ (ks << 6)));
      }
#pragma unroll
      for (int mi = 0; mi < 4; ++mi)
#pragma unroll
        for (int nj = 0; nj < 4; ++nj)
          acc[mi][nj] = __builtin_amdgcn_mfma_f32_16x16x32_bf16(
              af[mi], bv[nj], acc[mi][nj], 0, 0, 0);
    }
    __syncthreads();
  }

  // ---- epilogue: C/D frag layout col=lane&15, row=(lane>>4)*4+reg
  const int row0 = bm * 128 + wm * 64 + ((lane >> 4) << 2);
  const int col0 = bn * 128 + wn * 64 + (lane & 15);
#pragma unroll
  for (int mi = 0; mi < 4; ++mi) {
#pragma unroll
    for (int nj = 0; nj < 4; ++nj) {
#pragma unroll
      for (int rr = 0; rr < 4; ++rr) {
        const size_t idx =
            (size_t)(row0 + mi * 16 + rr) * N + (col0 + nj * 16);
        const float v = acc[mi][nj][rr];
        if (EPI == 0) {
          ((__hip_bfloat16*)Cv)[idx] = __float2bfloat16(v);
        } else if (EPI == 1) {
          const float g = __bfloat162float(Gin[idx]);
          ((__hip_bfloat16*)Cv)[idx] =
              __float2bfloat16(g / (1.0f + __expf(-g)) * v);
        } else {
          ((float*)Cv)[idx] = v;
        }
      }
    }
  }
}

// ---------------------------------------------------------------- launcher
extern "C" void kernel_launch(void* const* d_in, const int* in_sizes, int n_in,
                              void* d_out, int out_size, void* d_ws,
                              size_t ws_size, hipStream_t stream) {
  const float* x = (const float*)d_in[0];
  const int* gate_codes = (const int*)d_in[1];
  const float* gate_absmax = (const float*)d_in[2];
  const int* up_codes = (const int*)d_in[3];
  const float* up_absmax = (const float*)d_in[4];
  const int* down_codes = (const int*)d_in[5];
  const float* down_absmax = (const float*)d_in[6];

  char* ws = (char*)d_ws;
  __hip_bfloat16* xb = (__hip_bfloat16*)ws;                              // 16 MB
  __hip_bfloat16* Hb = (__hip_bfloat16*)(ws + (size_t)TDIM * HDIM * 2);  // 56 MB

  f32_to_bf16_k<<<2048, 256, 0, stream>>>(x, xb, (TDIM * HDIM) / 8);

  // gate: fused dequant+GEMM, store g (bf16)
  gemm_fused_k<0><<<(TDIM / 128) * (MDIM / 128), 256, 0, stream>>>(
      xb, gate_codes, gate_absmax, Hb, nullptr, TDIM, MDIM, HDIM);
  // up: fused dequant+GEMM, h = silu(g)*u in place
  gemm_fused_k<1><<<(TDIM / 128) * (MDIM / 128), 256, 0, stream>>>(
      xb, up_codes, up_absmax, Hb, Hb, TDIM, MDIM, HDIM);
  // down: fused dequant+GEMM, f32 out (no split-K, no atomics)
  gemm_fused_k<2><<<(TDIM / 128) * (HDIM / 128), 256, 0, stream>>>(
      Hb, down_codes, down_absmax, (float*)d_out, nullptr, TDIM, HDIM, MDIM);
}

// Round 9
// 1173.618 us; speedup vs baseline: 1.7141x; 1.7141x over previous
//
#include <hip/hip_runtime.h>
#include <hip/hip_bf16.h>
#include <cstdint>
#include <cstddef>

// Problem dims (fixed by setup_inputs)
#define TDIM 2048
#define HDIM 4096
#define MDIM 14336

typedef __attribute__((ext_vector_type(8))) __bf16 bf16x8;
typedef __attribute__((ext_vector_type(4))) float f32x4;

__device__ __constant__ float NF4_LUT[16] = {
    -1.0f, -0.6961928009986877f, -0.5250730514526367f, -0.39491748809814453f,
    -0.28444138169288635f, -0.18477343022823334f, -0.09105003625154495f, 0.0f,
    0.07958029955625534f, 0.16093020141124725f, 0.24611230194568634f,
    0.33791524171829224f, 0.44070982933044434f, 0.5626170039176941f,
    0.7229568362236023f, 1.0f};

__device__ __forceinline__ void g2l16(const void* g, void* l) {
  __builtin_amdgcn_global_load_lds(
      (const __attribute__((address_space(1))) unsigned int*)g,
      (__attribute__((address_space(3))) unsigned int*)l, 16, 0, 0);
}

// ------------------------------------------------------------ x f32 -> bf16
__global__ __launch_bounds__(256) void f32_to_bf16_k(
    const float* __restrict__ in, __hip_bfloat16* __restrict__ out, int n8) {
  for (int i = blockIdx.x * 256 + threadIdx.x; i < n8; i += gridDim.x * 256) {
    const float4* p = (const float4*)(in + (size_t)i * 8);
    float4 a = p[0], b = p[1];
    union { __hip_bfloat16 h[8]; int4 v; } u;
    u.h[0] = __float2bfloat16(a.x);
    u.h[1] = __float2bfloat16(a.y);
    u.h[2] = __float2bfloat16(a.z);
    u.h[3] = __float2bfloat16(a.w);
    u.h[4] = __float2bfloat16(b.x);
    u.h[5] = __float2bfloat16(b.y);
    u.h[6] = __float2bfloat16(b.z);
    u.h[7] = __float2bfloat16(b.w);
    *(int4*)(out + (size_t)i * 8) = u.v;
  }
}

// ---------------------------------- pack int32 codes -> 4-bit, TILE-MAJOR
// out[kt][n][32B]: byte q of (kt,n) = codes[n][kt*64+2q] | codes[..+2q+1]<<4
// -> a GEMM block's per-K-tile B read is 4KB fully contiguous.
__global__ __launch_bounds__(256) void pack_nf4_k(
    const int* __restrict__ in, uint8_t* __restrict__ out, int N, int K) {
  const int total = N * (K >> 6);
  for (int idx = blockIdx.x * 256 + threadIdx.x; idx < total;
       idx += gridDim.x * 256) {
    const int kt = idx / N;
    const int n = idx - kt * N;
    const int4* p = (const int4*)(in + (size_t)n * K + kt * 64);
    union { uint8_t b[32]; int4 v[2]; } u;
#pragma unroll
    for (int j = 0; j < 16; ++j) {
      const int4 c = p[j];
      u.b[2 * j] = (uint8_t)((c.x & 15) | ((c.y & 15) << 4));
      u.b[2 * j + 1] = (uint8_t)((c.z & 15) | ((c.w & 15) << 4));
    }
    int4* o = (int4*)(out + (size_t)idx * 32);
    o[0] = u.v[0];
    o[1] = u.v[1];
  }
}

// --------------------------- absmax [N][K/64] -> [K/64][N] (coalesced read)
__global__ __launch_bounds__(256) void transpose_am_k(
    const float* __restrict__ in, float* __restrict__ out, int N, int KB) {
  const int total = N * KB;
  for (int idx = blockIdx.x * 256 + threadIdx.x; idx < total;
       idx += gridDim.x * 256) {
    const int kt = idx / N;
    const int n = idx - kt * N;
    out[idx] = in[(size_t)n * KB + kt];
  }
}

// ------------------------- Fused packed-NF4-dequant 128x128 GEMM (R1 core)
// C[M,N] = A[M,K] @ dequant(Bp,amT)[N,K]^T, f32 acc.
// R1-proven skeleton (single-buffer, 2x __syncthreads, 4 waves 2x2, BK=64,
// g2l16 A staging, XOR-swizzled LDS, bm-major + XCD swizzle). B staged by
// in-register dequant from 4-bit tile-major codes: per K-tile each thread
// loads 16B packed (=32 weights, block's 4KB contiguous), 16 float2-LUT
// lookups, scale by per-(row,tile) absmax (BK=64==quant blk), 4 swizzled
// ds_write_b128 (write path identical to R8, verified). Next-tile codes+am
// register-prefetched under MFMA. Staged bytes/tile: 32KB -> 20.5KB.
// EPI: 0 = store bf16; 1 = silu(Gin)*acc -> bf16; 2 = store f32
template <int EPI>
__global__ __launch_bounds__(256, 3) void gemm_fused_k(
    const __hip_bfloat16* __restrict__ A, const uint8_t* __restrict__ Bp,
    const float* __restrict__ amT, void* __restrict__ Cv,
    const __hip_bfloat16* __restrict__ Gin, int M, int N, int K) {
  __shared__ __align__(16) char sA[128 * 128];
  __shared__ __align__(16) char sB[128 * 128];
  __shared__ float2 lut2[256];

  const int tid = threadIdx.x;
  const int lane = tid & 63;
  const int wid = tid >> 6;

  // pair LUT: entry i = (NF4[i&15], NF4[i>>4])  (low nibble = even col)
  lut2[tid] = make_float2(NF4_LUT[tid & 15], NF4_LUT[tid >> 4]);

  // bijective XCD swizzle (grids 1792/512, %8==0), bm-major decode (R1)
  const int nbn = N >> 7;
  const int nwg = (M >> 7) * nbn;
  const int cpx = nwg >> 3;
  const int bid = blockIdx.x;
  const int wg = (bid & 7) * cpx + (bid >> 3);
  const int bm = wg / nbn, bn = wg % nbn;

  // ---- A staging geometry (R1-exact)
  const int srow = lane >> 3;
  const int scolb = ((lane & 7) ^ srow) << 4;
  const char* gA = (const char*)A +
      ((size_t)(bm * 128 + wid * 8 + srow) * K) * 2 + scolb;
  const size_t cstep = (size_t)64 * K;  // 32 rows in bytes
  char* lA = sA + wid * 1024;

  // ---- B fused-dequant geometry: 2 threads/row, 32 weights each
  const int r = tid >> 1;
  const int h = tid & 1;
  const int Rrow = bn * 128 + r;
  const uint8_t* pb0 = Bp + (size_t)Rrow * 32 + h * 16;  // + kt*N*32
  const float* ab0 = amT + Rrow;                          // + kt*N
  char* bwr = sB + r * 128;
  const int rx = r & 7;

  // ---- fragment read bases (swizzled) — R1-exact
  const int wm = wid >> 1, wn = wid & 1;
  const int colsw = (((lane >> 4) << 4) ^ ((lane & 7) << 4));
  const int aoff = (wm * 64 + (lane & 15)) * 128 + colsw;
  const int boff = (wn * 64 + (lane & 15)) * 128 + colsw;

  f32x4 acc[4][4] = {};

  const int nt = K >> 6;
  int4 pk = *(const int4*)pb0;
  float am = ab0[0];

  __syncthreads();  // lut2 visible

  for (int kt = 0; kt < nt; ++kt) {
    // ---- dequant 32 weights -> 4 swizzled 16B chunks
    union { uint8_t b[16]; int4 v; } cu;
    cu.v = pk;
#pragma unroll
    for (int j = 0; j < 4; ++j) {
      union { __hip_bfloat16 bb[8]; int4 v; } ou;
#pragma unroll
      for (int p = 0; p < 4; ++p) {
        const float2 lv = lut2[cu.b[j * 4 + p]];
        ou.bb[2 * p] = __float2bfloat16(lv.x * am);
        ou.bb[2 * p + 1] = __float2bfloat16(lv.y * am);
      }
      *(int4*)(bwr + ((((h << 2) | j) ^ rx) << 4)) = ou.v;
    }
    // ---- stage A tile kt (async, drained at barrier)
    const char* pa = gA + (size_t)kt * 128;
#pragma unroll
    for (int c = 0; c < 4; ++c) g2l16(pa + c * cstep, lA + c * 4096);
    // ---- prefetch next codes + absmax (L2-hot, hidden under MFMA)
    if (kt + 1 < nt) {
      pk = *(const int4*)(pb0 + (size_t)(kt + 1) * N * 32);
      am = ab0[(size_t)(kt + 1) * N];
    }
    __syncthreads();
#pragma unroll
    for (int ks = 0; ks < 2; ++ks) {
      bf16x8 af[4], bv[4];
#pragma unroll
      for (int i = 0; i < 4; ++i) {
        af[i] = *(const bf16x8*)(sA + ((aoff + i * 2048) ^ (ks << 6)));
        bv[i] = *(const bf16x8*)(sB + ((boff + i * 2048) ^ (ks << 6)));
      }
#pragma unroll
      for (int mi = 0; mi < 4; ++mi)
#pragma unroll
        for (int nj = 0; nj < 4; ++nj)
          acc[mi][nj] = __builtin_amdgcn_mfma_f32_16x16x32_bf16(
              af[mi], bv[nj], acc[mi][nj], 0, 0, 0);
    }
    __syncthreads();
  }

  // ---- epilogue: C/D frag layout col=lane&15, row=(lane>>4)*4+reg
  const int row0 = bm * 128 + wm * 64 + ((lane >> 4) << 2);
  const int col0 = bn * 128 + wn * 64 + (lane & 15);
#pragma unroll
  for (int mi = 0; mi < 4; ++mi) {
#pragma unroll
    for (int nj = 0; nj < 4; ++nj) {
#pragma unroll
      for (int rr = 0; rr < 4; ++rr) {
        const size_t idx =
            (size_t)(row0 + mi * 16 + rr) * N + (col0 + nj * 16);
        const float v = acc[mi][nj][rr];
        if (EPI == 0) {
          ((__hip_bfloat16*)Cv)[idx] = __float2bfloat16(v);
        } else if (EPI == 1) {
          const float g = __bfloat162float(Gin[idx]);
          ((__hip_bfloat16*)Cv)[idx] =
              __float2bfloat16(g / (1.0f + __expf(-g)) * v);
        } else {
          ((float*)Cv)[idx] = v;
        }
      }
    }
  }
}

// ---------------------------------------------------------------- launcher
extern "C" void kernel_launch(void* const* d_in, const int* in_sizes, int n_in,
                              void* d_out, int out_size, void* d_ws,
                              size_t ws_size, hipStream_t stream) {
  const float* x = (const float*)d_in[0];
  const int* gate_codes = (const int*)d_in[1];
  const float* gate_absmax = (const float*)d_in[2];
  const int* up_codes = (const int*)d_in[3];
  const float* up_absmax = (const float*)d_in[4];
  const int* down_codes = (const int*)d_in[5];
  const float* down_absmax = (const float*)d_in[6];

  char* ws = (char*)d_ws;
  __hip_bfloat16* xb = (__hip_bfloat16*)ws;                    // 16.78 MB
  __hip_bfloat16* Hb = (__hip_bfloat16*)(ws + 16777216);       // 58.72 MB
  uint8_t* pg = (uint8_t*)(ws + 75497472);                     // 29.36 MB
  uint8_t* pu = (uint8_t*)(ws + 104857600);                    // 29.36 MB
  uint8_t* pd = (uint8_t*)(ws + 134217728);                    // 29.36 MB
  float* amg = (float*)(ws + 163577856);                       // 3.67 MB
  float* amu = (float*)(ws + 167247872);                       // 3.67 MB
  float* amd = (float*)(ws + 170917888);                       // 3.67 MB

  f32_to_bf16_k<<<2048, 256, 0, stream>>>(x, xb, (TDIM * HDIM) / 8);

  // pack codes (tile-major nibbles) + transpose absmax
  pack_nf4_k<<<2048, 256, 0, stream>>>(gate_codes, pg, MDIM, HDIM);
  pack_nf4_k<<<2048, 256, 0, stream>>>(up_codes, pu, MDIM, HDIM);
  pack_nf4_k<<<2048, 256, 0, stream>>>(down_codes, pd, HDIM, MDIM);
  transpose_am_k<<<2048, 256, 0, stream>>>(gate_absmax, amg, MDIM, HDIM / 64);
  transpose_am_k<<<2048, 256, 0, stream>>>(up_absmax, amu, MDIM, HDIM / 64);
  transpose_am_k<<<2048, 256, 0, stream>>>(down_absmax, amd, HDIM, MDIM / 64);

  // gate: fused, store g (bf16)
  gemm_fused_k<0><<<(TDIM / 128) * (MDIM / 128), 256, 0, stream>>>(
      xb, pg, amg, Hb, nullptr, TDIM, MDIM, HDIM);
  // up: fused, h = silu(g)*u in place
  gemm_fused_k<1><<<(TDIM / 128) * (MDIM / 128), 256, 0, stream>>>(
      xb, pu, amu, Hb, Hb, TDIM, MDIM, HDIM);
  // down: fused, f32 out
  gemm_fused_k<2><<<(TDIM / 128) * (HDIM / 128), 256, 0, stream>>>(
      Hb, pd, amd, (float*)d_out, nullptr, TDIM, HDIM, MDIM);
}